// Round 4
// baseline (973.096 us; speedup 1.0000x reference)
//
#include <hip/hip_runtime.h>
#include <cstddef>
#include <cstdint>

#define GAMMA_F 0.99f
#define OMG_F   0.01f      // 1 - gamma
#define EPS_F   1e-5f
#define KN 8192
#define DD 256
#define NN 32768           // B*T

// output layout (float offsets)
#define OFF_ZQ     0
#define OFF_COMMIT 8388608
#define OFF_IDX    8388609
#define OFF_EMB    8421377
#define OFF_MT     10518529
#define OFF_NT     12615681

#define LISTCAP 1048574u   // (emb region - 3 floats) / 2 floats per u64

typedef _Float16 half8 __attribute__((ext_vector_type(8)));
typedef _Float16 half4 __attribute__((ext_vector_type(4)));
typedef float    f32x4 __attribute__((ext_vector_type(4)));

// ---------------------------------------------------------------------------
// async 16B global->LDS (DMA: lane i -> lds_base + i*16; base wave-uniform,
// global address must be 16B aligned)
__device__ __forceinline__ void gload16(const void* g, void* l) {
    __builtin_amdgcn_global_load_lds(
        (const __attribute__((address_space(1))) unsigned int*)g,
        (__attribute__((address_space(3))) unsigned int*)l, 16, 0, 0);
}

// sortable pack: (monotone f32 bits << 32) | idx  -> u64 min == (dist, idx) min
__device__ __forceinline__ unsigned long long packdi(float dist, int n) {
    unsigned u = __float_as_uint(dist);
    u ^= (unsigned)((int)u >> 31) | 0x80000000u;
    return ((unsigned long long)u << 32) | (unsigned)n;
}

// ---------------------------------------------------------------------------
// fp32 -> f16 (RNE), vectorized
__global__ __launch_bounds__(256) void conv_hi_kernel(
    const float* __restrict__ x, _Float16* __restrict__ hi) {
    const size_t i0 = ((size_t)blockIdx.x * 256 + threadIdx.x) * 4;
    const float4 v = *(const float4*)(x + i0);
    half4 h;
    h[0] = (_Float16)v.x; h[1] = (_Float16)v.y;
    h[2] = (_Float16)v.z; h[3] = (_Float16)v.w;
    *(half4*)(hi + i0) = h;
}

// ---------------------------------------------------------------------------
// ||w_k||^2 per code (fp32)
__global__ __launch_bounds__(64) void wsq_kernel(const float* __restrict__ W,
                                                 float* __restrict__ wsq) {
    const int k = blockIdx.x;
    const int lane = threadIdx.x;
    const float4 v = *(const float4*)(W + (size_t)k * DD + lane * 4);
    float s = v.x * v.x + v.y * v.y + v.z * v.z + v.w * v.w;
#pragma unroll
    for (int off = 32; off > 0; off >>= 1) s += __shfl_down(s, off, 64);
    if (lane == 0) wsq[k] = s;
}

// ---------------------------------------------------------------------------
// Screening GEMM: single f16 pass, K=256. 128 pts x 128 codes per block.
// Epilogue: per (point, code-tile) top-2 -> packed (f32 d1, u16 c1, u16 c2).
__global__ __launch_bounds__(256) void screen_kernel(
    const _Float16* __restrict__ zh, const _Float16* __restrict__ wh,
    const float* __restrict__ wsq, unsigned long long* __restrict__ tmin2) {
    __shared__ __align__(16) char smem[65536];   // tiles 32KB / cand 64KB
    _Float16* As = (_Float16*)smem;              // 128*64 halfs
    _Float16* Bs = As + 128 * 64;

    const int tid  = threadIdx.x;
    const int wave = tid >> 6;
    const int lane = tid & 63;
    const int quad = lane >> 4;
    const int col  = lane & 15;
    const int wm = (wave >> 1) * 64;
    const int wn = (wave & 1) * 64;

    const int bm = blockIdx.x >> 6;
    const int bn = blockIdx.x & 63;
    const int m0 = bm * 128;
    const int n0 = bn * 128;

    f32x4 acc[4][4];
#pragma unroll
    for (int i = 0; i < 4; i++)
#pragma unroll
        for (int j = 0; j < 4; j++) acc[i][j] = (f32x4){0.f, 0.f, 0.f, 0.f};

    for (int c = 0; c < 4; ++c) {            // K = 256, 4 chunks of 64
        const int d0 = c * 64;
        __syncthreads();
#pragma unroll
        for (int i = 0; i < 4; ++i) {
            const int clin = (wave * 4 + i) * 64 + lane;   // 0..1023
            const int mrow = clin >> 3;
            const int p = clin & 7;
            const int q = p ^ (mrow & 7);                  // swizzled k-chunk
            gload16(zh + (size_t)(m0 + mrow) * DD + d0 + q * 8,
                    As + (wave * 4 + i) * 512);
            gload16(wh + (size_t)(n0 + mrow) * DD + d0 + q * 8,
                    Bs + (wave * 4 + i) * 512);
        }
        __syncthreads();

#pragma unroll
        for (int kk = 0; kk < 2; ++kk) {
            half8 a[4], b[4];
#pragma unroll
            for (int t = 0; t < 4; ++t) {
                const int mr = wm + t * 16 + col;
                const int nr = wn + t * 16 + col;
                const int cc = kk * 4 + quad;
                a[t] = *(const half8*)(As + mr * 64 + (cc ^ (mr & 7)) * 8);
                b[t] = *(const half8*)(Bs + nr * 64 + (cc ^ (nr & 7)) * 8);
            }
#pragma unroll
            for (int ti = 0; ti < 4; ++ti)
#pragma unroll
                for (int tj = 0; tj < 4; ++tj)
                    acc[ti][tj] = __builtin_amdgcn_mfma_f32_16x16x32_f16(
                        a[ti], b[tj], acc[ti][tj], 0, 0, 0);
        }
    }

    float wq[4];
#pragma unroll
    for (int tj = 0; tj < 4; ++tj) wq[tj] = wsq[n0 + wn + tj * 16 + col];

    __syncthreads();                        // tiles dead; reuse smem as cand
    unsigned long long* cand = (unsigned long long*)smem;  // [128][32][2]
    const int ccol = col + 16 * (wave & 1);
#pragma unroll
    for (int ti = 0; ti < 4; ++ti) {
#pragma unroll
        for (int v = 0; v < 4; ++v) {
            unsigned long long t0 = ~0ull, t1 = ~0ull;
#pragma unroll
            for (int tj = 0; tj < 4; ++tj) {
                const float dist = fmaf(-2.0f, acc[ti][tj][v], wq[tj]);
                const unsigned long long pk =
                    packdi(dist, n0 + wn + tj * 16 + col);
                if (pk < t0) { t1 = t0; t0 = pk; }
                else if (pk < t1) { t1 = pk; }
            }
            const int m = wm + ti * 16 + quad * 4 + v;
            cand[m * 64 + ccol * 2 + 0] = t0;
            cand[m * 64 + ccol * 2 + 1] = t1;
        }
    }
    __syncthreads();
    if (tid < 128) {
        const int m = tid;
        unsigned long long t0 = ~0ull, t1 = ~0ull;
        for (int j = 0; j < 64; ++j) {
            const int jj = (j + tid) & 63;           // stagger banks
            const unsigned long long v = cand[m * 64 + jj];
            if (v < t0) { t1 = t0; t0 = v; }
            else if (v < t1) { t1 = v; }
        }
        unsigned u = (unsigned)(t0 >> 32);           // un-monotone -> f32 bits
        u = (u & 0x80000000u) ? (u ^ 0x80000000u) : ~u;
        const unsigned long long ent =
            (unsigned long long)u |
            ((unsigned long long)((unsigned)t0 & 0xffffu) << 32) |
            ((unsigned long long)((unsigned)t1 & 0xffffu) << 48);
        tmin2[(size_t)(m0 + m) * 64 + bn] = ent;
    }
}

// ---------------------------------------------------------------------------
// Per point: min over 64 tile records; append all codes within window to list.
__global__ __launch_bounds__(256) void compact_kernel(
    const unsigned long long* __restrict__ tmin2,
    unsigned* __restrict__ counter, unsigned long long* __restrict__ list) {
    const int tid = threadIdx.x;
    const int lane = tid & 63;
    const int n = blockIdx.x * 4 + (tid >> 6);
    const unsigned long long e = tmin2[(size_t)n * 64 + lane];
    const float d1 = __uint_as_float((unsigned)e);
    float mn = d1;
#pragma unroll
    for (int off = 32; off > 0; off >>= 1)
        mn = fminf(mn, __shfl_xor(mn, off, 64));
    const bool q = d1 <= mn + 1.0f;      // 26-sigma screen-error window
    const unsigned long long bal = __ballot(q);
    int base = 0;
    if (lane == 0) base = (int)atomicAdd(counter, 2u * (unsigned)__popcll(bal));
    base = __shfl(base, 0, 64);
    if (q) {
        const int rank = __popcll(bal & ((1ull << lane) - 1ull));
        const int p = base + 2 * rank;
        if (p + 1 < (int)LISTCAP) {
            const unsigned c1 = (unsigned)(e >> 32) & 0xffffu;
            const unsigned c2 = (unsigned)(e >> 48);
            list[p]     = ((unsigned long long)c1 << 32) | (unsigned)n;
            list[p + 1] = ((unsigned long long)c2 << 32) | (unsigned)n;
        }
    }
}

// ---------------------------------------------------------------------------
// Exact fp32 rescoring of candidates; one wave per list entry (grid-stride).
__global__ __launch_bounds__(256) void rescore_kernel(
    const float* __restrict__ ze, const float* __restrict__ W,
    const unsigned* __restrict__ counter,
    const unsigned long long* __restrict__ list,
    unsigned long long* __restrict__ cells) {
    const int tid = threadIdx.x;
    const int lane = tid & 63;
    const unsigned gw = blockIdx.x * 4 + (tid >> 6);
    unsigned total = *counter;
    if (total > LISTCAP) total = LISTCAP;
    for (unsigned i = gw; i < total; i += 4096) {
        const unsigned long long ent = list[i];
        const unsigned n = (unsigned)ent;
        const unsigned c = (unsigned)(ent >> 32);
        const float4 z = *(const float4*)(ze + (size_t)n * DD + lane * 4);
        const float4 w = *(const float4*)(W + (size_t)c * DD + lane * 4);
        float dot = z.x * w.x + z.y * w.y + z.z * w.z + z.w * w.w;
        float wq2 = w.x * w.x + w.y * w.y + w.z * w.z + w.w * w.w;
#pragma unroll
        for (int off = 32; off > 0; off >>= 1) {
            dot += __shfl_xor(dot, off, 64);
            wq2 += __shfl_xor(wq2, off, 64);
        }
        const float dist = fmaf(-2.0f, dot, wq2);
        if (lane == 0) atomicMin(&cells[n], packdi(dist, (int)c));
    }
}

// ---------------------------------------------------------------------------
__global__ __launch_bounds__(256) void idx_write_kernel(
    const unsigned long long* __restrict__ cells, float* __restrict__ idxf) {
    const int i = blockIdx.x * 256 + threadIdx.x;
    idxf[i] = (float)(unsigned)(cells[i] & 0xFFFFFFFFull);
}

// ---------------------------------------------------------------------------
// Gather zq, write zq_st, commit-loss reduce, one-hot scatter (atomics).
__global__ __launch_bounds__(256) void gather_scatter_kernel(
    const float* __restrict__ ze, const float* __restrict__ W,
    const float* __restrict__ idxf, float* __restrict__ zq_out,
    float* __restrict__ commit_acc, float* __restrict__ mt_acc,
    float* __restrict__ nt_acc) {
    const int tid = threadIdx.x;
    const int n = blockIdx.x * 4 + (tid >> 6);
    const int lane = tid & 63;
    const int idx = (int)idxf[n];

    const float4 z = *(const float4*)(ze + (size_t)n * DD + lane * 4);
    const float4 w = *(const float4*)(W + (size_t)idx * DD + lane * 4);

    float4 d, o;
    d.x = w.x - z.x; d.y = w.y - z.y; d.z = w.z - z.z; d.w = w.w - z.w;
    o.x = z.x + d.x; o.y = z.y + d.y; o.z = z.z + d.z; o.w = z.w + d.w;
    *(float4*)(zq_out + (size_t)n * DD + lane * 4) = o;

    float* mp = mt_acc + (size_t)idx * DD + lane * 4;
    atomicAdd(mp + 0, OMG_F * z.x);
    atomicAdd(mp + 1, OMG_F * z.y);
    atomicAdd(mp + 2, OMG_F * z.z);
    atomicAdd(mp + 3, OMG_F * z.w);
    if (lane == 0) atomicAdd(nt_acc + idx, OMG_F);

    float c = d.x * d.x + d.y * d.y + d.z * d.z + d.w * d.w;
#pragma unroll
    for (int off = 32; off > 0; off >>= 1) c += __shfl_down(c, off, 64);

    __shared__ float wsum[4];
    if (lane == 0) wsum[tid >> 6] = c;
    __syncthreads();
    if (tid == 0) {
        const float part = wsum[0] + wsum[1] + wsum[2] + wsum[3];
        atomicAdd(commit_acc, part * (1.0f / 8388608.0f));
    }
}

// ---------------------------------------------------------------------------
__global__ __launch_bounds__(256) void finalize_nt_kernel(
    const float* __restrict__ Nt_in, float* __restrict__ nt_acc) {
    const int k = blockIdx.x * 256 + threadIdx.x;
    nt_acc[k] += GAMMA_F * Nt_in[k];
}

// ---------------------------------------------------------------------------
__global__ __launch_bounds__(256) void final_kernel(
    const float* __restrict__ mt_in, const float* __restrict__ nt_new,
    float* __restrict__ mt_out, float* __restrict__ emb_out) {
    __shared__ float red[256];
    float s = 0.0f;
    for (int i = threadIdx.x; i < KN; i += 256) s += nt_new[i];
    red[threadIdx.x] = s;
    __syncthreads();
    for (int off = 128; off > 0; off >>= 1) {
        if (threadIdx.x < off) red[threadIdx.x] += red[threadIdx.x + off];
        __syncthreads();
    }
    const float n = red[0];

    const size_t i0 = ((size_t)blockIdx.x * 256 + threadIdx.x) * 4;
    const int k = (int)(i0 >> 8);

    const float4 st = *(const float4*)(mt_out + i0);
    const float4 mt = *(const float4*)(mt_in + i0);
    float4 mnew;
    mnew.x = GAMMA_F * mt.x + st.x;
    mnew.y = GAMMA_F * mt.y + st.y;
    mnew.z = GAMMA_F * mt.z + st.z;
    mnew.w = GAMMA_F * mt.w + st.w;
    *(float4*)(mt_out + i0) = mnew;

    const float Nn = (nt_new[k] + EPS_F) * n / (n + (float)KN * EPS_F);
    float4 e;
    e.x = mnew.x / Nn;
    e.y = mnew.y / Nn;
    e.z = mnew.z / Nn;
    e.w = mnew.w / Nn;
    *(float4*)(emb_out + i0) = e;
}

// ---------------------------------------------------------------------------
extern "C" void kernel_launch(void* const* d_in, const int* in_sizes, int n_in,
                              void* d_out, int out_size, void* d_ws, size_t ws_size,
                              hipStream_t stream) {
    const float* ze = (const float*)d_in[0];
    const float* W  = (const float*)d_in[1];
    const float* mt = (const float*)d_in[2];
    const float* Nt = (const float*)d_in[3];

    float* out    = (float*)d_out;
    float* zq_out = out + OFF_ZQ;
    float* commit = out + OFF_COMMIT;
    float* idxf   = out + OFF_IDX;
    float* emb    = out + OFF_EMB;
    float* mtn    = out + OFF_MT;
    float* ntn    = out + OFF_NT;

    // ---- scratch aliases (aligned; all consumed before real outputs written)
    _Float16* zh = (_Float16*)zq_out;                  // NN*DD halfs (16.7 MB)
    unsigned long long* tmin2 =                        // NN*64 u64 (16.78 MB)
        (unsigned long long*)(zq_out + (size_t)NN * DD / 2);
    _Float16* wh = (_Float16*)(mtn + 3);               // byte 16B-aligned
    unsigned long long* cells =                        // NN u64, 8B-aligned
        (unsigned long long*)(mtn + 1048581);
    float* wsqbuf = idxf;                              // KN floats (scratch)
    unsigned* counter = (unsigned*)(emb + 1);
    unsigned long long* list = (unsigned long long*)(emb + 3);

    // 1) f16 conversions
    conv_hi_kernel<<<(NN * DD / 4) / 256, 256, 0, stream>>>(ze, zh);
    conv_hi_kernel<<<(KN * DD / 4) / 256, 256, 0, stream>>>(W, wh);

    // 2) ||w||^2 (fp32) into idx-region scratch
    wsq_kernel<<<KN, 64, 0, stream>>>(W, wsqbuf);

    // 3) init candidate counter + per-point cells
    hipMemsetAsync(counter, 0, sizeof(unsigned), stream);
    hipMemsetAsync(cells, 0xFF, sizeof(unsigned long long) * NN, stream);

    // 4) f16 screening GEMM -> per-(point,tile) top-2 records
    screen_kernel<<<(NN / 128) * (KN / 128), 256, 0, stream>>>(
        zh, wh, wsqbuf, tmin2);

    // 5) window compaction -> candidate list
    compact_kernel<<<NN / 4, 256, 0, stream>>>(tmin2, counter, list);

    // 6) exact fp32 rescoring -> cells (packed (dist, idx) atomicMin)
    rescore_kernel<<<1024, 256, 0, stream>>>(ze, W, counter, list, cells);

    // 7) winning indices (overwrites wsq scratch — already consumed)
    idx_write_kernel<<<NN / 256, 256, 0, stream>>>(cells, idxf);

    // 8) zero accumulation regions (kills wh + cells scratch)
    hipMemsetAsync(commit, 0, sizeof(float), stream);
    hipMemsetAsync(mtn, 0, sizeof(float) * (size_t)KN * DD, stream);
    hipMemsetAsync(ntn, 0, sizeof(float) * KN, stream);

    // 9) gather + commit loss + one-hot scatter (overwrites zh/tmin2)
    gather_scatter_kernel<<<NN / 4, 256, 0, stream>>>(ze, W, idxf, zq_out,
                                                      commit, mtn, ntn);

    // 10) EMA blend for Nt
    finalize_nt_kernel<<<KN / 256, 256, 0, stream>>>(Nt, ntn);

    // 11) mt_new, n, Nn, embedW_new (overwrites list/counter scratch)
    final_kernel<<<(KN * DD / 4) / 256, 256, 0, stream>>>(mt, ntn, mtn, emb);
}

// Round 5
// 585.677 us; speedup vs baseline: 1.6615x; 1.6615x over previous
//
#include <hip/hip_runtime.h>
#include <cstddef>
#include <cstdint>

#define GAMMA_F 0.99f
#define OMG_F   0.01f      // 1 - gamma
#define EPS_F   1e-5f
#define KN 8192
#define DD 256
#define NN 32768           // B*T

// output layout (float offsets)
#define OFF_ZQ     0
#define OFF_COMMIT 8388608
#define OFF_IDX    8388609
#define OFF_EMB    8421377
#define OFF_MT     10518529
#define OFF_NT     12615681

typedef _Float16 half8 __attribute__((ext_vector_type(8)));
typedef _Float16 half4 __attribute__((ext_vector_type(4)));
typedef float    f32x4 __attribute__((ext_vector_type(4)));

// ---------------------------------------------------------------------------
// async 16B global->LDS (DMA: lane i -> lds_base + i*16; base wave-uniform,
// global address must be 16B aligned)
__device__ __forceinline__ void gload16(const void* g, void* l) {
    __builtin_amdgcn_global_load_lds(
        (const __attribute__((address_space(1))) unsigned int*)g,
        (__attribute__((address_space(3))) unsigned int*)l, 16, 0, 0);
}

// sortable pack: (monotone f32 bits << 32) | idx  -> u64 min == (dist, idx) min
__device__ __forceinline__ unsigned long long packdi(float dist, int n) {
    unsigned u = __float_as_uint(dist);
    u ^= (unsigned)((int)u >> 31) | 0x80000000u;
    return ((unsigned long long)u << 32) | (unsigned)n;
}

// ---------------------------------------------------------------------------
// fp32 -> f16 (RNE), vectorized
__global__ __launch_bounds__(256) void conv_hi_kernel(
    const float* __restrict__ x, _Float16* __restrict__ hi) {
    const size_t i0 = ((size_t)blockIdx.x * 256 + threadIdx.x) * 4;
    const float4 v = *(const float4*)(x + i0);
    half4 h;
    h[0] = (_Float16)v.x; h[1] = (_Float16)v.y;
    h[2] = (_Float16)v.z; h[3] = (_Float16)v.w;
    *(half4*)(hi + i0) = h;
}

// ---------------------------------------------------------------------------
// ||w_k||^2 per code (fp32)
__global__ __launch_bounds__(64) void wsq_kernel(const float* __restrict__ W,
                                                 float* __restrict__ wsq) {
    const int k = blockIdx.x;
    const int lane = threadIdx.x;
    const float4 v = *(const float4*)(W + (size_t)k * DD + lane * 4);
    float s = v.x * v.x + v.y * v.y + v.z * v.z + v.w * v.w;
#pragma unroll
    for (int off = 32; off > 0; off >>= 1) s += __shfl_down(s, off, 64);
    if (lane == 0) wsq[k] = s;
}

// ---------------------------------------------------------------------------
// Screening GEMM: single f16 pass, K=256. 128 pts x 128 codes per block.
// Epilogue: per (point, code-tile) top-2 -> packed (f32 d1, u16 c1, u16 c2).
__global__ __launch_bounds__(256) void screen_kernel(
    const _Float16* __restrict__ zh, const _Float16* __restrict__ wh,
    const float* __restrict__ wsq, unsigned long long* __restrict__ tmin2) {
    __shared__ __align__(16) char smem[65536];   // tiles 32KB / cand 64KB
    _Float16* As = (_Float16*)smem;              // 128*64 halfs
    _Float16* Bs = As + 128 * 64;

    const int tid  = threadIdx.x;
    const int wave = tid >> 6;
    const int lane = tid & 63;
    const int quad = lane >> 4;
    const int col  = lane & 15;
    const int wm = (wave >> 1) * 64;
    const int wn = (wave & 1) * 64;

    const int bm = blockIdx.x >> 6;
    const int bn = blockIdx.x & 63;
    const int m0 = bm * 128;
    const int n0 = bn * 128;

    f32x4 acc[4][4];
#pragma unroll
    for (int i = 0; i < 4; i++)
#pragma unroll
        for (int j = 0; j < 4; j++) acc[i][j] = (f32x4){0.f, 0.f, 0.f, 0.f};

    for (int c = 0; c < 4; ++c) {            // K = 256, 4 chunks of 64
        const int d0 = c * 64;
        __syncthreads();
#pragma unroll
        for (int i = 0; i < 4; ++i) {
            const int clin = (wave * 4 + i) * 64 + lane;   // 0..1023
            const int mrow = clin >> 3;
            const int p = clin & 7;
            const int q = p ^ (mrow & 7);                  // swizzled k-chunk
            gload16(zh + (size_t)(m0 + mrow) * DD + d0 + q * 8,
                    As + (wave * 4 + i) * 512);
            gload16(wh + (size_t)(n0 + mrow) * DD + d0 + q * 8,
                    Bs + (wave * 4 + i) * 512);
        }
        __syncthreads();

#pragma unroll
        for (int kk = 0; kk < 2; ++kk) {
            half8 a[4], b[4];
#pragma unroll
            for (int t = 0; t < 4; ++t) {
                const int mr = wm + t * 16 + col;
                const int nr = wn + t * 16 + col;
                const int cc = kk * 4 + quad;
                a[t] = *(const half8*)(As + mr * 64 + (cc ^ (mr & 7)) * 8);
                b[t] = *(const half8*)(Bs + nr * 64 + (cc ^ (nr & 7)) * 8);
            }
#pragma unroll
            for (int ti = 0; ti < 4; ++ti)
#pragma unroll
                for (int tj = 0; tj < 4; ++tj)
                    acc[ti][tj] = __builtin_amdgcn_mfma_f32_16x16x32_f16(
                        a[ti], b[tj], acc[ti][tj], 0, 0, 0);
        }
    }

    float wq[4];
#pragma unroll
    for (int tj = 0; tj < 4; ++tj) wq[tj] = wsq[n0 + wn + tj * 16 + col];

    __syncthreads();                        // tiles dead; reuse smem as cand
    unsigned long long* cand = (unsigned long long*)smem;  // [128][32][2]
    const int ccol = col + 16 * (wave & 1);
#pragma unroll
    for (int ti = 0; ti < 4; ++ti) {
#pragma unroll
        for (int v = 0; v < 4; ++v) {
            unsigned long long t0 = ~0ull, t1 = ~0ull;
#pragma unroll
            for (int tj = 0; tj < 4; ++tj) {
                const float dist = fmaf(-2.0f, acc[ti][tj][v], wq[tj]);
                const unsigned long long pk =
                    packdi(dist, n0 + wn + tj * 16 + col);
                if (pk < t0) { t1 = t0; t0 = pk; }
                else if (pk < t1) { t1 = pk; }
            }
            const int m = wm + ti * 16 + quad * 4 + v;
            cand[m * 64 + ccol * 2 + 0] = t0;
            cand[m * 64 + ccol * 2 + 1] = t1;
        }
    }
    __syncthreads();
    if (tid < 128) {
        const int m = tid;
        unsigned long long t0 = ~0ull, t1 = ~0ull;
        for (int j = 0; j < 64; ++j) {
            const int jj = (j + tid) & 63;           // stagger banks
            const unsigned long long v = cand[m * 64 + jj];
            if (v < t0) { t1 = t0; t0 = v; }
            else if (v < t1) { t1 = v; }
        }
        unsigned u = (unsigned)(t0 >> 32);           // un-monotone -> f32 bits
        u = (u & 0x80000000u) ? (u ^ 0x80000000u) : ~u;
        const unsigned long long ent =
            (unsigned long long)u |
            ((unsigned long long)((unsigned)t0 & 0xffffu) << 32) |
            ((unsigned long long)((unsigned)t1 & 0xffffu) << 48);
        tmin2[(size_t)(m0 + m) * 64 + bn] = ent;
    }
}

// ---------------------------------------------------------------------------
// Per point (one wave, exclusive owner): min over 64 tile records; write all
// codes within window into the point's private slot array. NO atomics.
__global__ __launch_bounds__(256) void compact_kernel(
    const unsigned long long* __restrict__ tmin2,
    unsigned* __restrict__ cnt, unsigned* __restrict__ slots) {
    const int tid = threadIdx.x;
    const int lane = tid & 63;
    const int n = blockIdx.x * 4 + (tid >> 6);
    const unsigned long long e = tmin2[(size_t)n * 64 + lane];
    const float d1 = __uint_as_float((unsigned)e);
    float mn = d1;
#pragma unroll
    for (int off = 32; off > 0; off >>= 1)
        mn = fminf(mn, __shfl_xor(mn, off, 64));
    const bool q = d1 <= mn + 1.0f;      // 26-sigma screen-error window
    const unsigned long long bal = __ballot(q);
    if (q) {
        const int rank = __popcll(bal & ((1ull << lane) - 1ull));
        if (rank < 16) {
            slots[(size_t)n * 32 + 2 * rank + 0] = (unsigned)(e >> 32) & 0xffffu;
            slots[(size_t)n * 32 + 2 * rank + 1] = (unsigned)(e >> 48);
        }
    }
    if (lane == 0) {
        unsigned c = 2u * (unsigned)__popcll(bal);
        cnt[n] = c < 32u ? c : 32u;
    }
}

// ---------------------------------------------------------------------------
// Exact fp32 rescoring: one wave per point; loop over its candidates; write
// the winning index directly. No atomics.
__global__ __launch_bounds__(256) void rescore_kernel(
    const float* __restrict__ ze, const float* __restrict__ W,
    const unsigned* __restrict__ cnt, const unsigned* __restrict__ slots,
    float* __restrict__ idxf) {
    const int tid = threadIdx.x;
    const int lane = tid & 63;
    const int n = blockIdx.x * 4 + (tid >> 6);
    const float4 z = *(const float4*)(ze + (size_t)n * DD + lane * 4);
    const unsigned m = cnt[n];
    unsigned long long best = ~0ull;
    for (unsigned j = 0; j < m; ++j) {
        const unsigned c = slots[(size_t)n * 32 + j];
        const float4 w = *(const float4*)(W + (size_t)c * DD + lane * 4);
        float dot = z.x * w.x + z.y * w.y + z.z * w.z + z.w * w.w;
        float wq  = w.x * w.x + w.y * w.y + w.z * w.z + w.w * w.w;
#pragma unroll
        for (int off = 32; off > 0; off >>= 1) {
            dot += __shfl_xor(dot, off, 64);
            wq  += __shfl_xor(wq, off, 64);
        }
        const float dist = fmaf(-2.0f, dot, wq);
        const unsigned long long pk = packdi(dist, (int)c);
        best = best < pk ? best : pk;
    }
    if (lane == 0) idxf[n] = (float)(unsigned)(best & 0xFFFFFFFFull);
}

// ---------------------------------------------------------------------------
// Gather zq, write zq_st, commit-loss reduce, one-hot scatter (atomics).
__global__ __launch_bounds__(256) void gather_scatter_kernel(
    const float* __restrict__ ze, const float* __restrict__ W,
    const float* __restrict__ idxf, float* __restrict__ zq_out,
    float* __restrict__ commit_acc, float* __restrict__ mt_acc,
    float* __restrict__ nt_acc) {
    const int tid = threadIdx.x;
    const int n = blockIdx.x * 4 + (tid >> 6);
    const int lane = tid & 63;
    const int idx = (int)idxf[n];

    const float4 z = *(const float4*)(ze + (size_t)n * DD + lane * 4);
    const float4 w = *(const float4*)(W + (size_t)idx * DD + lane * 4);

    float4 d, o;
    d.x = w.x - z.x; d.y = w.y - z.y; d.z = w.z - z.z; d.w = w.w - z.w;
    o.x = z.x + d.x; o.y = z.y + d.y; o.z = z.z + d.z; o.w = z.w + d.w;
    *(float4*)(zq_out + (size_t)n * DD + lane * 4) = o;

    float* mp = mt_acc + (size_t)idx * DD + lane * 4;
    atomicAdd(mp + 0, OMG_F * z.x);
    atomicAdd(mp + 1, OMG_F * z.y);
    atomicAdd(mp + 2, OMG_F * z.z);
    atomicAdd(mp + 3, OMG_F * z.w);
    if (lane == 0) atomicAdd(nt_acc + idx, OMG_F);

    float c = d.x * d.x + d.y * d.y + d.z * d.z + d.w * d.w;
#pragma unroll
    for (int off = 32; off > 0; off >>= 1) c += __shfl_down(c, off, 64);

    __shared__ float wsum[4];
    if (lane == 0) wsum[tid >> 6] = c;
    __syncthreads();
    if (tid == 0) {
        const float part = wsum[0] + wsum[1] + wsum[2] + wsum[3];
        atomicAdd(commit_acc, part * (1.0f / 8388608.0f));
    }
}

// ---------------------------------------------------------------------------
__global__ __launch_bounds__(256) void finalize_nt_kernel(
    const float* __restrict__ Nt_in, float* __restrict__ nt_acc) {
    const int k = blockIdx.x * 256 + threadIdx.x;
    nt_acc[k] += GAMMA_F * Nt_in[k];
}

// ---------------------------------------------------------------------------
__global__ __launch_bounds__(256) void final_kernel(
    const float* __restrict__ mt_in, const float* __restrict__ nt_new,
    float* __restrict__ mt_out, float* __restrict__ emb_out) {
    __shared__ float red[256];
    float s = 0.0f;
    for (int i = threadIdx.x; i < KN; i += 256) s += nt_new[i];
    red[threadIdx.x] = s;
    __syncthreads();
    for (int off = 128; off > 0; off >>= 1) {
        if (threadIdx.x < off) red[threadIdx.x] += red[threadIdx.x + off];
        __syncthreads();
    }
    const float n = red[0];

    const size_t i0 = ((size_t)blockIdx.x * 256 + threadIdx.x) * 4;
    const int k = (int)(i0 >> 8);

    const float4 st = *(const float4*)(mt_out + i0);
    const float4 mt = *(const float4*)(mt_in + i0);
    float4 mnew;
    mnew.x = GAMMA_F * mt.x + st.x;
    mnew.y = GAMMA_F * mt.y + st.y;
    mnew.z = GAMMA_F * mt.z + st.z;
    mnew.w = GAMMA_F * mt.w + st.w;
    *(float4*)(mt_out + i0) = mnew;

    const float Nn = (nt_new[k] + EPS_F) * n / (n + (float)KN * EPS_F);
    float4 e;
    e.x = mnew.x / Nn;
    e.y = mnew.y / Nn;
    e.z = mnew.z / Nn;
    e.w = mnew.w / Nn;
    *(float4*)(emb_out + i0) = e;
}

// ---------------------------------------------------------------------------
extern "C" void kernel_launch(void* const* d_in, const int* in_sizes, int n_in,
                              void* d_out, int out_size, void* d_ws, size_t ws_size,
                              hipStream_t stream) {
    const float* ze = (const float*)d_in[0];
    const float* W  = (const float*)d_in[1];
    const float* mt = (const float*)d_in[2];
    const float* Nt = (const float*)d_in[3];

    float* out    = (float*)d_out;
    float* zq_out = out + OFF_ZQ;
    float* commit = out + OFF_COMMIT;
    float* idxf   = out + OFF_IDX;
    float* emb    = out + OFF_EMB;
    float* mtn    = out + OFF_MT;
    float* ntn    = out + OFF_NT;

    // ---- scratch aliases (aligned; all consumed before real outputs written)
    _Float16* zh = (_Float16*)zq_out;                  // NN*DD halfs (16.7 MB)
    unsigned long long* tmin2 =                        // NN*64 u64 (16.78 MB)
        (unsigned long long*)(zq_out + (size_t)NN * DD / 2);
    _Float16* wh = (_Float16*)(mtn + 3);               // 16B-aligned
    float* wsqbuf = idxf;                              // KN floats (scratch;
                                                       // overwritten by rescore)
    unsigned* cnt   = (unsigned*)emb;                  // NN u32
    unsigned* slots = (unsigned*)emb + NN;             // NN*32 u32 (4.2 MB)

    // 1) f16 conversions
    conv_hi_kernel<<<(NN * DD / 4) / 256, 256, 0, stream>>>(ze, zh);
    conv_hi_kernel<<<(KN * DD / 4) / 256, 256, 0, stream>>>(W, wh);

    // 2) ||w||^2 (fp32) into idx-region scratch
    wsq_kernel<<<KN, 64, 0, stream>>>(W, wsqbuf);

    // 3) f16 screening GEMM -> per-(point,tile) top-2 records
    screen_kernel<<<(NN / 128) * (KN / 128), 256, 0, stream>>>(
        zh, wh, wsqbuf, tmin2);

    // 4) window compaction -> per-point candidate slots (atomic-free)
    compact_kernel<<<NN / 4, 256, 0, stream>>>(tmin2, cnt, slots);

    // 5) exact fp32 rescoring -> winning indices written directly
    rescore_kernel<<<NN / 4, 256, 0, stream>>>(ze, W, cnt, slots, idxf);

    // 6) zero accumulation regions (kills wh scratch)
    hipMemsetAsync(commit, 0, sizeof(float), stream);
    hipMemsetAsync(mtn, 0, sizeof(float) * (size_t)KN * DD, stream);
    hipMemsetAsync(ntn, 0, sizeof(float) * KN, stream);

    // 7) gather + commit loss + one-hot scatter (overwrites zh/tmin2)
    gather_scatter_kernel<<<NN / 4, 256, 0, stream>>>(ze, W, idxf, zq_out,
                                                      commit, mtn, ntn);

    // 8) EMA blend for Nt
    finalize_nt_kernel<<<KN / 256, 256, 0, stream>>>(Nt, ntn);

    // 9) mt_new, n, Nn, embedW_new (overwrites cnt/slots scratch)
    final_kernel<<<(KN * DD / 4) / 256, 256, 0, stream>>>(mt, ntn, mtn, emb);
}